// Round 12
// baseline (204.046 us; speedup 1.0000x reference)
//
#include <hip/hip_runtime.h>

#define ALPHA 0.2f
#define BB 4
#define NN 2048
#define IC 256
#define OC 32

// ---------------------------------------------------------------------------
// Kernel 1 (frozen, r4 form): h = features @ W; f1 = h@a[:OC]; f2 = h@a[OC:]
// ---------------------------------------------------------------------------
__global__ void k1_hproj(const float* __restrict__ feat,
                         const float* __restrict__ W,
                         const float* __restrict__ a,
                         float* __restrict__ h,
                         float* __restrict__ f1,
                         float* __restrict__ f2) {
    __shared__ float s_feat[IC];
    int row = blockIdx.x;           // b*N + n
    int tid = threadIdx.x;          // 0..63
    ((float4*)s_feat)[tid] = ((const float4*)(feat + (size_t)row * IC))[tid];
    __syncthreads();
    if (tid < OC) {
        int c = tid;
        float acc = 0.f;
        #pragma unroll 8
        for (int k = 0; k < IC; ++k)
            acc += s_feat[k] * W[k * OC + c];
        h[(size_t)row * OC + c] = acc;
        float v1 = acc * a[c];
        float v2 = acc * a[OC + c];
        #pragma unroll
        for (int m = 16; m >= 1; m >>= 1) {
            v1 += __shfl_xor(v1, m, 64);
            v2 += __shfl_xor(v2, m, 64);
        }
        if (c == 0) { f1[row] = v1; f2[row] = v2; }
    }
}

// ---------------------------------------------------------------------------
// FUSED k2+k3: block = 2 i-rows x ALL 4 batches (batches share cij!).
//  Phase 1: stream distance[i0:i0+2,:,:] (512KB/block, 1KB/wave-instr) ->
//           cij rows in LDS. No global cij round-trip.
//  Phase 2: wave w = row (i_local=w>>2, b=w&3); register softmax (r6 math),
//           f2/adj from global (L2-hot), p -> LDS fp16.
//  Phase 3: PV; 4 h-row float4 loads per j (one per batch), each reused for
//           2 rows; h is 1MB total -> L3-resident across all blocks.
//  Phase 4: cross-wave reduce via s_fin aliased INTO s_cij (post-barrier).
// LDS ~48.2KB -> 3 blocks/CU; phases of co-resident blocks skew to keep the
// HBM stream continuously fed.
// ---------------------------------------------------------------------------
__global__ __launch_bounds__(512) void k23_fused(
        const float* __restrict__ f1,
        const float* __restrict__ f2,
        const float* __restrict__ h,
        const float* __restrict__ We,
        const float* __restrict__ distance,
        const int* __restrict__ adj,
        float* __restrict__ out) {
    __shared__ float s_cij[2][NN];      // 16 KB; aliased as s_fin in phase 3/4
    __shared__ _Float16 s_p[8][NN];     // 32 KB
    __shared__ float s_den[8];
    int tid  = threadIdx.x;             // 0..511
    int wv   = tid >> 6;
    int lane = tid & 63;
    int i0   = blockIdx.x * 2;

    // --- phase 1: cij[i_local][j] = sum_c distance[i0+i_local, j, c] * We[c]
    {
        int g8 = tid >> 3;              // element slot 0..63
        int r  = tid & 7;
        float4 w = ((const float4*)We)[r];
        const float4* d4 = (const float4*)distance + (size_t)i0 * NN * 8;
        #pragma unroll 4
        for (int t = 0; t < 64; ++t) {
            int e = t * 64 + g8;        // 0..4095 = (i_local<<11) | j
            float4 d = d4[(size_t)e * 8 + r];
            float v = d.x * w.x + d.y * w.y + d.z * w.z + d.w * w.w;
            v += __shfl_xor(v, 1, 64);
            v += __shfl_xor(v, 2, 64);
            v += __shfl_xor(v, 4, 64);
            if (r == 0) s_cij[e >> 11][e & (NN - 1)] = v;
        }
    }
    __syncthreads();

    // --- phase 2: scores + softmax; wave wv owns row (il, b)
    {
        int il = wv >> 2, b = wv & 3;
        int i  = i0 + il;
        float f1i = f1[(size_t)b * NN + i];
        const float* f2b    = f2 + (size_t)b * NN;
        const int*   adjrow = adj + (size_t)i * NN;
        float sc[NN / 64];
        float lmax = -1e30f;
        #pragma unroll
        for (int k = 0; k < NN / 64; ++k) {
            int j = lane + 64 * k;
            float e = f1i + f2b[j];
            e = e > 0.f ? e : ALPHA * e;
            float s = ((adjrow[j] > 0) || (j == i)) ? (e + s_cij[il][j]) : -1e30f;
            sc[k] = s;
            lmax = fmaxf(lmax, s);
        }
        #pragma unroll
        for (int m = 32; m >= 1; m >>= 1) lmax = fmaxf(lmax, __shfl_xor(lmax, m, 64));
        float lsum = 0.f;
        #pragma unroll
        for (int k = 0; k < NN / 64; ++k) {
            float p = __expf(sc[k] - lmax);
            s_p[wv][lane + 64 * k] = (_Float16)p;
            lsum += p;
        }
        #pragma unroll
        for (int m = 32; m >= 1; m >>= 1) lsum += __shfl_xor(lsum, m, 64);
        if (lane == 0) s_den[wv] = lsum;
    }
    __syncthreads();   // s_p/s_den published; all s_cij reads complete

    // --- phase 3: PV. g = j-slot (64 groups of 8), c4 = c-quad.
    float* s_fin = &s_cij[0][0];        // alias: fin(wq,c4,rr,q) safe post-barrier
    {
        int g  = tid >> 3;
        int c4 = tid & 7;
        float acc[8][4];
        #pragma unroll
        for (int rr = 0; rr < 8; ++rr)
            { acc[rr][0] = acc[rr][1] = acc[rr][2] = acc[rr][3] = 0.f; }
        #pragma unroll 2
        for (int k = 0; k < NN / 64; ++k) {
            int j = g + 64 * k;
            float4 hv[4];
            #pragma unroll
            for (int b = 0; b < 4; ++b)
                hv[b] = *(const float4*)(h + ((size_t)b * NN + j) * OC + c4 * 4);
            #pragma unroll
            for (int il = 0; il < 2; ++il) {
                #pragma unroll
                for (int b = 0; b < 4; ++b) {
                    int rr = il * 4 + b;
                    float p = (float)s_p[rr][j];
                    acc[rr][0] += p * hv[b].x;
                    acc[rr][1] += p * hv[b].y;
                    acc[rr][2] += p * hv[b].z;
                    acc[rr][3] += p * hv[b].w;
                }
            }
        }
        #pragma unroll
        for (int rr = 0; rr < 8; ++rr) {
            #pragma unroll
            for (int q = 0; q < 4; ++q) {
                float v = acc[rr][q];
                v += __shfl_xor(v, 8, 64);
                v += __shfl_xor(v, 16, 64);
                v += __shfl_xor(v, 32, 64);
                acc[rr][q] = v;
            }
        }
        if (lane < 8) {                 // lane == its c4; g-bits reduced away
            #pragma unroll
            for (int rr = 0; rr < 8; ++rr)
                #pragma unroll
                for (int q = 0; q < 4; ++q)
                    s_fin[(((wv * 8 + lane) * 8) + rr) * 4 + q] = acc[rr][q];
        }
    }
    __syncthreads();

    // --- phase 4: final reduce + store (256 outputs: 8 rows x 32 cols)
    if (tid < 8 * OC) {
        int rr = tid >> 5, c = tid & 31;
        float v = 0.f;
        #pragma unroll
        for (int wq = 0; wq < 8; ++wq)
            v += s_fin[(((wq * 8 + (c >> 2)) * 8) + rr) * 4 + (c & 3)];
        int il = rr >> 2, b = rr & 3;
        out[((size_t)b * NN + (i0 + il)) * OC + c] = v / s_den[rr];
    }
}

extern "C" void kernel_launch(void* const* d_in, const int* in_sizes, int n_in,
                              void* d_out, int out_size, void* d_ws, size_t ws_size,
                              hipStream_t stream) {
    const float* feat     = (const float*)d_in[0];  // [B,N,IC]
    const float* W        = (const float*)d_in[1];  // [IC,OC]
    const float* a        = (const float*)d_in[2];  // [2*OC,1]
    const float* We       = (const float*)d_in[3];  // [OC,1]
    const float* distance = (const float*)d_in[4];  // [N,N,OC]
    const int*   adj      = (const int*)d_in[5];    // [N,N]
    float* out = (float*)d_out;

    float* ws  = (float*)d_ws;
    float* h   = ws;                       // B*N*OC
    float* f1  = h  + (size_t)BB * NN * OC;
    float* f2  = f1 + (size_t)BB * NN;

    k1_hproj<<<BB * NN, 64, 0, stream>>>(feat, W, a, h, f1, f2);
    k23_fused<<<NN / 2, 512, 0, stream>>>(f1, f2, h, We, distance, adj, out);
}

// Round 13
// 134.913 us; speedup vs baseline: 1.5124x; 1.5124x over previous
//
#include <hip/hip_runtime.h>

#define ALPHA 0.2f
#define BB 4
#define NN 2048
#define IC 256
#define OC 32
#define TI 8                      // i-rows per k3 block (one wave per row)

// ---------------------------------------------------------------------------
// Kernel 1 (frozen, r4 form): h = features @ W; f1 = h@a[:OC]; f2 = h@a[OC:]
// ---------------------------------------------------------------------------
__global__ void k1_hproj(const float* __restrict__ feat,
                         const float* __restrict__ W,
                         const float* __restrict__ a,
                         float* __restrict__ h,
                         float* __restrict__ f1,
                         float* __restrict__ f2) {
    __shared__ float s_feat[IC];
    int row = blockIdx.x;           // b*N + n
    int tid = threadIdx.x;          // 0..63
    ((float4*)s_feat)[tid] = ((const float4*)(feat + (size_t)row * IC))[tid];
    __syncthreads();
    if (tid < OC) {
        int c = tid;
        float acc = 0.f;
        #pragma unroll 8
        for (int k = 0; k < IC; ++k)
            acc += s_feat[k] * W[k * OC + c];
        h[(size_t)row * OC + c] = acc;
        float v1 = acc * a[c];
        float v2 = acc * a[OC + c];
        #pragma unroll
        for (int m = 16; m >= 1; m >>= 1) {
            v1 += __shfl_xor(v1, m, 64);
            v2 += __shfl_xor(v2, m, 64);
        }
        if (c == 0) { f1[row] = v1; f2[row] = v2; }
    }
}

// ---------------------------------------------------------------------------
// Kernel 2 (MASK-GATED): cij[i,j] = sum_c distance[i,j,c]*We[c], ONLY where
// mask=(adj|I). Unmasked entries get softmax weight exactly 0 in k3, so their
// distance chunks (~50% of 512MB) are dead bytes -- skip them.
//  - block = row i. Wave wv compacts j-segment [wv*512,+512) via ballot/popc
//    into LDS (u16), order-preserving within segment.
//  - gather: 8 lanes/elem, 8 elems/wave-instr = 8 x 128B fully-consumed lines
//    per instruction (same line count/instr as the proven r4 pattern).
//  - row accumulated in LDS; full 8KB row written coalesced (unmasked = 0.0).
// ---------------------------------------------------------------------------
__global__ void k2_cij_masked(const float* __restrict__ distance,
                              const float* __restrict__ We,
                              const int* __restrict__ adj,
                              float* __restrict__ cij) {
    __shared__ unsigned short s_idx[4][512];   // 4 KB
    __shared__ int s_cnt[4];
    __shared__ float s_crow[NN];               // 8 KB
    int i    = blockIdx.x;
    int tid  = threadIdx.x;        // 0..255
    int wv   = tid >> 6;
    int lane = tid & 63;
    const int* arow = adj + (size_t)i * NN;

    // --- compact masked j's of segment [wv*512, wv*512+512) (in-wave scan)
    int base = 0;
    #pragma unroll
    for (int k = 0; k < 8; ++k) {
        int j = wv * 512 + k * 64 + lane;
        bool m = (arow[j] > 0) || (j == i);
        unsigned long long bal = __ballot(m);
        int pos = __popcll(bal & ((1ull << lane) - 1ull));
        if (m) s_idx[wv][base + pos] = (unsigned short)j;
        base += __popcll(bal);
    }
    if (lane == 0) s_cnt[wv] = base;
    // --- zero the row accumulator (unmasked entries stay 0.0: deterministic)
    #pragma unroll
    for (int q = 0; q < 2; ++q)
        ((float4*)s_crow)[q * 256 + tid] = make_float4(0.f, 0.f, 0.f, 0.f);
    __syncthreads();

    // --- gather + reduce masked elements
    int g8 = tid >> 3;             // element slot 0..31
    int r  = tid & 7;
    float4 w = ((const float4*)We)[r];
    const float4* drow = (const float4*)distance + (size_t)i * NN * 8;
    for (int seg = 0; seg < 4; ++seg) {
        int n = s_cnt[seg];
        for (int b2 = 0; b2 < n; b2 += 32) {
            int e = b2 + g8;
            if (e < n) {           // uniform within each 8-lane group
                int j = s_idx[seg][e];
                float4 d = drow[(size_t)j * 8 + r];
                float v = d.x * w.x + d.y * w.y + d.z * w.z + d.w * w.w;
                v += __shfl_xor(v, 1, 64);
                v += __shfl_xor(v, 2, 64);
                v += __shfl_xor(v, 4, 64);
                if (r == 0) s_crow[j] = v;
            }
        }
    }
    __syncthreads();

    // --- coalesced full-row store (2 float4 per thread)
    float* crow = cij + (size_t)i * NN;
    #pragma unroll
    for (int q = 0; q < 2; ++q)
        ((float4*)crow)[q * 256 + tid] = ((float4*)s_crow)[q * 256 + tid];
}

// ---------------------------------------------------------------------------
// Kernel 3 (frozen, r6 form, measured ~57 us): fp16 p-tile, f2 in LDS.
// ---------------------------------------------------------------------------
__global__ void k3_attn(const float* __restrict__ f1,
                        const float* __restrict__ f2,
                        const float* __restrict__ h,
                        const float* __restrict__ cij,
                        const int* __restrict__ adj,
                        float* __restrict__ out) {
    __shared__ _Float16 s_p[TI][NN];       // 32 KB
    __shared__ float s_f2[NN];             // 8 KB
    __shared__ float s_den[TI];
    __shared__ float s_fin[8][8][TI][4];   // 8 KB
    int bt = blockIdx.x;                   // 0..1023
    int b  = bt >> 8;                      // NN/TI = 256 tiles
    int i0 = (bt & 255) * TI;
    int tid = threadIdx.x;                 // 0..511
    int wv = tid >> 6;
    int lane = tid & 63;

    ((float4*)s_f2)[tid] = ((const float4*)(f2 + (size_t)b * NN))[tid];
    __syncthreads();

    {
        int i  = i0 + wv;
        int bi = b * NN + i;
        float f1i = f1[bi];
        const int*   adjrow = adj + (size_t)i * NN;
        const float* cijrow = cij + (size_t)i * NN;
        float sc[NN / 64];
        float lmax = -1e30f;
        #pragma unroll
        for (int k = 0; k < NN / 64; ++k) {
            int j = lane + 64 * k;
            float e = f1i + s_f2[j];
            e = e > 0.f ? e : ALPHA * e;
            float s = ((adjrow[j] > 0) || (j == i)) ? (e + cijrow[j]) : -1e30f;
            sc[k] = s;
            lmax = fmaxf(lmax, s);
        }
        #pragma unroll
        for (int m = 32; m >= 1; m >>= 1) lmax = fmaxf(lmax, __shfl_xor(lmax, m, 64));
        float lsum = 0.f;
        #pragma unroll
        for (int k = 0; k < NN / 64; ++k) {
            float p = __expf(sc[k] - lmax);
            s_p[wv][lane + 64 * k] = (_Float16)p;
            lsum += p;
        }
        #pragma unroll
        for (int m = 32; m >= 1; m >>= 1) lsum += __shfl_xor(lsum, m, 64);
        if (lane == 0) s_den[wv] = lsum;
    }
    __syncthreads();

    const float* hb = h + (size_t)b * NN * OC;
    int g  = tid >> 3;          // 0..63
    int c4 = tid & 7;           // 0..7
    float acc[TI][4];
    #pragma unroll
    for (int r = 0; r < TI; ++r) { acc[r][0] = acc[r][1] = acc[r][2] = acc[r][3] = 0.f; }
    #pragma unroll 4
    for (int k = 0; k < NN / 64; ++k) {
        int j = g + 64 * k;
        float4 hv = *(const float4*)(hb + (size_t)j * OC + c4 * 4);
        #pragma unroll
        for (int r = 0; r < TI; ++r) {
            float p = (float)s_p[r][j];
            acc[r][0] += p * hv.x;
            acc[r][1] += p * hv.y;
            acc[r][2] += p * hv.z;
            acc[r][3] += p * hv.w;
        }
    }
    #pragma unroll
    for (int r = 0; r < TI; ++r) {
        #pragma unroll
        for (int q = 0; q < 4; ++q) {
            float v = acc[r][q];
            v += __shfl_xor(v, 8, 64);
            v += __shfl_xor(v, 16, 64);
            v += __shfl_xor(v, 32, 64);
            acc[r][q] = v;
        }
    }
    if ((tid & 56) == 0) {
        #pragma unroll
        for (int r = 0; r < TI; ++r)
            #pragma unroll
            for (int q = 0; q < 4; ++q)
                s_fin[wv][c4][r][q] = acc[r][q];
    }
    __syncthreads();
    if (tid < TI * OC) {
        int r = tid >> 5, c = tid & 31;
        float v = 0.f;
        #pragma unroll
        for (int wq = 0; wq < 8; ++wq) v += s_fin[wq][c >> 2][r][c & 3];
        out[((size_t)b * NN + i0 + r) * OC + c] = v / s_den[r];
    }
}

extern "C" void kernel_launch(void* const* d_in, const int* in_sizes, int n_in,
                              void* d_out, int out_size, void* d_ws, size_t ws_size,
                              hipStream_t stream) {
    const float* feat     = (const float*)d_in[0];  // [B,N,IC]
    const float* W        = (const float*)d_in[1];  // [IC,OC]
    const float* a        = (const float*)d_in[2];  // [2*OC,1]
    const float* We       = (const float*)d_in[3];  // [OC,1]
    const float* distance = (const float*)d_in[4];  // [N,N,OC]
    const int*   adj      = (const int*)d_in[5];    // [N,N]
    float* out = (float*)d_out;

    float* ws  = (float*)d_ws;
    float* h   = ws;                       // B*N*OC
    float* f1  = h  + (size_t)BB * NN * OC;
    float* f2  = f1 + (size_t)BB * NN;
    float* cij = f2 + (size_t)BB * NN;     // N*N

    k1_hproj<<<BB * NN, 64, 0, stream>>>(feat, W, a, h, f1, f2);
    k2_cij_masked<<<NN, 256, 0, stream>>>(distance, We, adj, cij);
    k3_attn<<<BB * NN / TI, 512, 0, stream>>>(f1, f2, h, cij, adj, out);
}

// Round 14
// 106.236 us; speedup vs baseline: 1.9207x; 1.2699x over previous
//
#include <hip/hip_runtime.h>

#define ALPHA 0.2f
#define BB 4
#define NN 2048
#define IC 256
#define OC 32
#define TI 8                      // i-rows per k3 block (one wave per row)

// ---------------------------------------------------------------------------
// Kernel 1 (frozen, r4 form): h = features @ W; f1 = h@a[:OC]; f2 = h@a[OC:]
// ---------------------------------------------------------------------------
__global__ void k1_hproj(const float* __restrict__ feat,
                         const float* __restrict__ W,
                         const float* __restrict__ a,
                         float* __restrict__ h,
                         float* __restrict__ f1,
                         float* __restrict__ f2) {
    __shared__ float s_feat[IC];
    int row = blockIdx.x;           // b*N + n
    int tid = threadIdx.x;          // 0..63
    ((float4*)s_feat)[tid] = ((const float4*)(feat + (size_t)row * IC))[tid];
    __syncthreads();
    if (tid < OC) {
        int c = tid;
        float acc = 0.f;
        #pragma unroll 8
        for (int k = 0; k < IC; ++k)
            acc += s_feat[k] * W[k * OC + c];
        h[(size_t)row * OC + c] = acc;
        float v1 = acc * a[c];
        float v2 = acc * a[OC + c];
        #pragma unroll
        for (int m = 16; m >= 1; m >>= 1) {
            v1 += __shfl_xor(v1, m, 64);
            v2 += __shfl_xor(v2, m, 64);
        }
        if (c == 0) { f1[row] = v1; f2[row] = v2; }
    }
}

// ---------------------------------------------------------------------------
// Kernel 2 (r13 structure + SENTINEL): cij[i,j] = sum_c distance[i,j,c]*We[c]
// where mask=(adj|I); UNMASKED entries now carry -1e30 (softmax-kill sentinel)
// so k3 needs no adj reads at all. ~50% of the 512MB stream stays skipped.
// ---------------------------------------------------------------------------
__global__ void k2_cij_masked(const float* __restrict__ distance,
                              const float* __restrict__ We,
                              const int* __restrict__ adj,
                              float* __restrict__ cij) {
    __shared__ unsigned short s_idx[4][512];   // 4 KB
    __shared__ int s_cnt[4];
    __shared__ float s_crow[NN];               // 8 KB
    int i    = blockIdx.x;
    int tid  = threadIdx.x;        // 0..255
    int wv   = tid >> 6;
    int lane = tid & 63;
    const int* arow = adj + (size_t)i * NN;

    // --- compact masked j's of segment [wv*512, wv*512+512) (in-wave scan)
    int base = 0;
    #pragma unroll
    for (int k = 0; k < 8; ++k) {
        int j = wv * 512 + k * 64 + lane;
        bool m = (arow[j] > 0) || (j == i);
        unsigned long long bal = __ballot(m);
        int pos = __popcll(bal & ((1ull << lane) - 1ull));
        if (m) s_idx[wv][base + pos] = (unsigned short)j;
        base += __popcll(bal);
    }
    if (lane == 0) s_cnt[wv] = base;
    // --- init row accumulator to the kill-sentinel (unmasked -> p == 0 in k3)
    #pragma unroll
    for (int q = 0; q < 2; ++q)
        ((float4*)s_crow)[q * 256 + tid] = make_float4(-1e30f, -1e30f, -1e30f, -1e30f);
    __syncthreads();

    // --- gather + reduce masked elements
    int g8 = tid >> 3;             // element slot 0..31
    int r  = tid & 7;
    float4 w = ((const float4*)We)[r];
    const float4* drow = (const float4*)distance + (size_t)i * NN * 8;
    for (int seg = 0; seg < 4; ++seg) {
        int n = s_cnt[seg];
        for (int b2 = 0; b2 < n; b2 += 32) {
            int e = b2 + g8;
            if (e < n) {           // uniform within each 8-lane group
                int j = s_idx[seg][e];
                float4 d = drow[(size_t)j * 8 + r];
                float v = d.x * w.x + d.y * w.y + d.z * w.z + d.w * w.w;
                v += __shfl_xor(v, 1, 64);
                v += __shfl_xor(v, 2, 64);
                v += __shfl_xor(v, 4, 64);
                if (r == 0) s_crow[j] = v;
            }
        }
    }
    __syncthreads();

    // --- coalesced full-row store (2 float4 per thread)
    float* crow = cij + (size_t)i * NN;
    #pragma unroll
    for (int q = 0; q < 2; ++q)
        ((float4*)crow)[q * 256 + tid] = ((float4*)s_crow)[q * 256 + tid];
}

// ---------------------------------------------------------------------------
// Kernel 3 (VECTORIZED score phase): no adj reads (sentinel in cij);
// cij/f2 read as float4 (8 loads/lane, was 64 scalar); p stored as packed
// fp16 quads. Lane owns j in {4*(lane+64k) .. +3}; butterfly reductions are
// partition-agnostic. PV phase unchanged (r6 form).
// ---------------------------------------------------------------------------
__global__ void k3_attn(const float* __restrict__ f1,
                        const float* __restrict__ f2,
                        const float* __restrict__ h,
                        const float* __restrict__ cij,
                        float* __restrict__ out) {
    __shared__ _Float16 s_p[TI][NN];       // 32 KB
    __shared__ float s_f2[NN];             // 8 KB
    __shared__ float s_den[TI];
    __shared__ float s_fin[8][8][TI][4];   // 8 KB
    int bt = blockIdx.x;                   // 0..1023
    int b  = bt >> 8;                      // NN/TI = 256 tiles
    int i0 = (bt & 255) * TI;
    int tid = threadIdx.x;                 // 0..511
    int wv = tid >> 6;
    int lane = tid & 63;

    ((float4*)s_f2)[tid] = ((const float4*)(f2 + (size_t)b * NN))[tid];
    __syncthreads();

    {
        int i  = i0 + wv;
        int bi = b * NN + i;
        float f1i = f1[bi];
        const float4* c4row = (const float4*)(cij + (size_t)i * NN);
        const float4* f4row = (const float4*)s_f2;
        float sc[32];
        float lmax = -1e30f;
        #pragma unroll
        for (int k = 0; k < 8; ++k) {
            int j4 = lane + 64 * k;            // float4 index
            float4 cv = c4row[j4];
            float4 fv = f4row[j4];
            #pragma unroll
            for (int e = 0; e < 4; ++e) {
                float ee = f1i + ((const float*)&fv)[e];
                ee = ee > 0.f ? ee : ALPHA * ee;
                float s = ee + ((const float*)&cv)[e];   // sentinel absorbs ee
                sc[k * 4 + e] = s;
                lmax = fmaxf(lmax, s);
            }
        }
        #pragma unroll
        for (int m = 32; m >= 1; m >>= 1) lmax = fmaxf(lmax, __shfl_xor(lmax, m, 64));
        float lsum = 0.f;
        #pragma unroll
        for (int k = 0; k < 8; ++k) {
            int j4 = lane + 64 * k;
            _Float16 pq[4];
            #pragma unroll
            for (int e = 0; e < 4; ++e) {
                float p = __expf(sc[k * 4 + e] - lmax);
                pq[e] = (_Float16)p;
                lsum += p;
            }
            *(short4*)&s_p[wv][j4 * 4] = *(short4*)pq;   // 8B packed store
        }
        #pragma unroll
        for (int m = 32; m >= 1; m >>= 1) lsum += __shfl_xor(lsum, m, 64);
        if (lane == 0) s_den[wv] = lsum;
    }
    __syncthreads();

    const float* hb = h + (size_t)b * NN * OC;
    int g  = tid >> 3;          // 0..63
    int c4 = tid & 7;           // 0..7
    float acc[TI][4];
    #pragma unroll
    for (int r = 0; r < TI; ++r) { acc[r][0] = acc[r][1] = acc[r][2] = acc[r][3] = 0.f; }
    #pragma unroll 4
    for (int k = 0; k < NN / 64; ++k) {
        int j = g + 64 * k;
        float4 hv = *(const float4*)(hb + (size_t)j * OC + c4 * 4);
        #pragma unroll
        for (int r = 0; r < TI; ++r) {
            float p = (float)s_p[r][j];
            acc[r][0] += p * hv.x;
            acc[r][1] += p * hv.y;
            acc[r][2] += p * hv.z;
            acc[r][3] += p * hv.w;
        }
    }
    #pragma unroll
    for (int r = 0; r < TI; ++r) {
        #pragma unroll
        for (int q = 0; q < 4; ++q) {
            float v = acc[r][q];
            v += __shfl_xor(v, 8, 64);
            v += __shfl_xor(v, 16, 64);
            v += __shfl_xor(v, 32, 64);
            acc[r][q] = v;
        }
    }
    if ((tid & 56) == 0) {
        #pragma unroll
        for (int r = 0; r < TI; ++r)
            #pragma unroll
            for (int q = 0; q < 4; ++q)
                s_fin[wv][c4][r][q] = acc[r][q];
    }
    __syncthreads();
    if (tid < TI * OC) {
        int r = tid >> 5, c = tid & 31;
        float v = 0.f;
        #pragma unroll
        for (int wq = 0; wq < 8; ++wq) v += s_fin[wq][c >> 2][r][c & 3];
        out[((size_t)b * NN + i0 + r) * OC + c] = v / s_den[r];
    }
}

extern "C" void kernel_launch(void* const* d_in, const int* in_sizes, int n_in,
                              void* d_out, int out_size, void* d_ws, size_t ws_size,
                              hipStream_t stream) {
    const float* feat     = (const float*)d_in[0];  // [B,N,IC]
    const float* W        = (const float*)d_in[1];  // [IC,OC]
    const float* a        = (const float*)d_in[2];  // [2*OC,1]
    const float* We       = (const float*)d_in[3];  // [OC,1]
    const float* distance = (const float*)d_in[4];  // [N,N,OC]
    const int*   adj      = (const int*)d_in[5];    // [N,N]
    float* out = (float*)d_out;

    float* ws  = (float*)d_ws;
    float* h   = ws;                       // B*N*OC
    float* f1  = h  + (size_t)BB * NN * OC;
    float* f2  = f1 + (size_t)BB * NN;
    float* cij = f2 + (size_t)BB * NN;     // N*N

    k1_hproj<<<BB * NN, 64, 0, stream>>>(feat, W, a, h, f1, f2);
    k2_cij_masked<<<NN, 256, 0, stream>>>(distance, We, adj, cij);
    k3_attn<<<BB * NN / TI, 512, 0, stream>>>(f1, f2, h, cij, out);
}